// Round 13
// baseline (6230.018 us; speedup 1.0000x reference)
//
#include <hip/hip_runtime.h>
#include <hip/hip_bf16.h>
#include <hip/hip_cooperative_groups.h>
#include <math.h>

namespace cg = cooperative_groups;

#define B 256
#define S 64
#define E 256
#define H 512
#define NC 32000

typedef __attribute__((ext_vector_type(8))) short short8;   // 8 bf16 = 4 VGPR
typedef __attribute__((ext_vector_type(4))) short short4v;
typedef __attribute__((ext_vector_type(4))) float f32x4;

__device__ inline short f2bf(float v) {
    __hip_bfloat16 h = __float2bfloat16(v);
    return *reinterpret_cast<short*>(&h);
}
__device__ inline float bf2f(short s) {
    __hip_bfloat16 h;
    *reinterpret_cast<short*>(&h) = s;
    return __bfloat162float(h);
}

// ---------------------------------------------------------------------------
__global__ __launch_bounds__(256) void k_zero(float4* __restrict__ p, int n4) {
    int i = blockIdx.x * 256 + threadIdx.x;
    if (i < n4) p[i] = float4{0.f, 0.f, 0.f, 0.f};
}

// ---------------------------------------------------------------------------
// gate-blocked transpose: outT[k][g*512+u] = Wg[u][k]   (Wg is [H][K])
__global__ __launch_bounds__(256) void k_trans(const float* __restrict__ W0,
                                               const float* __restrict__ W1,
                                               const float* __restrict__ W2,
                                               const float* __restrict__ W3,
                                               int K, float* __restrict__ outT) {
    __shared__ float TT[64][65];   // [k_local][u_local]
    const int u0 = blockIdx.x * 64;
    const int k0 = blockIdx.y * 64;
    const int g  = blockIdx.z;
    const float* Wg = (g == 0) ? W0 : (g == 1) ? W1 : (g == 2) ? W2 : W3;
    const int tx = threadIdx.x & 15, ty = threadIdx.x >> 4;
#pragma unroll
    for (int i = 0; i < 4; ++i) {
        float4 v = *(const float4*)(Wg + (size_t)(u0 + ty + i * 16) * K + k0 + tx * 4);
        TT[tx * 4 + 0][ty + i * 16] = v.x;
        TT[tx * 4 + 1][ty + i * 16] = v.y;
        TT[tx * 4 + 2][ty + i * 16] = v.z;
        TT[tx * 4 + 3][ty + i * 16] = v.w;
    }
    __syncthreads();
#pragma unroll
    for (int i = 0; i < 4; ++i) {
        int kl = ty + i * 16;
        float4 o = {TT[kl][tx * 4 + 0], TT[kl][tx * 4 + 1], TT[kl][tx * 4 + 2], TT[kl][tx * 4 + 3]};
        *(float4*)(outT + (size_t)(k0 + kl) * 2048 + g * 512 + u0 + tx * 4) = o;
    }
}

// ---------------------------------------------------------------------------
// combined layer-1 x-path: WcT[k][g*512+u] = sum_e Wi_g[u][e] * W[e][k]
__global__ __launch_bounds__(256) void k_comb(const float* __restrict__ Wi0,
                                              const float* __restrict__ Wi1,
                                              const float* __restrict__ Wi2,
                                              const float* __restrict__ Wi3,
                                              const float* __restrict__ W,
                                              float* __restrict__ WcT) {
    __shared__ float WiS[64][65];   // [u_local][e_local]
    __shared__ float WS[64][65];    // [e_local][k_local]
    const int g  = blockIdx.x >> 3;
    const int u0 = (blockIdx.x & 7) * 64;
    const int k0 = blockIdx.y * 64;
    const float* Wi = (g == 0) ? Wi0 : (g == 1) ? Wi1 : (g == 2) ? Wi2 : Wi3;
    const int tx = threadIdx.x & 15, ty = threadIdx.x >> 4;
    float acc[4][4] = {};   // [ui][kj]
    for (int e0 = 0; e0 < E; e0 += 64) {
#pragma unroll
        for (int i = 0; i < 4; ++i) {
            float4 v = *(const float4*)(Wi + (size_t)(u0 + ty + i * 16) * E + e0 + tx * 4);
            *(float4*)&WiS[ty + i * 16][tx * 4] = v;
        }
#pragma unroll
        for (int i = 0; i < 4; ++i) {
            float4 v = *(const float4*)(W + (size_t)(e0 + ty + i * 16) * H + k0 + tx * 4);
            *(float4*)&WS[ty + i * 16][tx * 4] = v;
        }
        __syncthreads();
#pragma unroll
        for (int el = 0; el < 64; ++el) {
            float uv[4], kv[4];
#pragma unroll
            for (int j = 0; j < 4; ++j) { uv[j] = WiS[ty * 4 + j][el]; kv[j] = WS[el][tx * 4 + j]; }
#pragma unroll
            for (int i2 = 0; i2 < 4; ++i2)
#pragma unroll
                for (int j = 0; j < 4; ++j) acc[i2][j] += uv[i2] * kv[j];
        }
        __syncthreads();
    }
#pragma unroll
    for (int j = 0; j < 4; ++j) {
        float4 o = {acc[0][j], acc[1][j], acc[2][j], acc[3][j]};
        *(float4*)(WcT + (size_t)(k0 + tx * 4 + j) * 2048 + g * 512 + u0 + ty * 4) = o;
    }
}

// ---------------------------------------------------------------------------
// biases (gate-blocked): bias0[g*512+u]=b_g[u]; bias1 += sum_e Wi_g[u][e]*b[e]
__global__ __launch_bounds__(256) void k_bias(const float* __restrict__ WxT,
                                              const float* __restrict__ bi,
                                              const float* __restrict__ bf_,
                                              const float* __restrict__ bg_,
                                              const float* __restrict__ bo_,
                                              const float* __restrict__ bvec,
                                              float* __restrict__ bias0,
                                              float* __restrict__ bias1) {
    int c = blockIdx.x * 256 + threadIdx.x;  // 2048
    int g = c >> 9, u = c & 511;
    const float* bp = (g == 0) ? bi : (g == 1) ? bf_ : (g == 2) ? bg_ : bo_;
    float basev = bp[u];
    float s = 0.f;
    for (int e = 0; e < E; ++e) s += WxT[(size_t)e * 2048 + c] * bvec[e];
    bias0[c] = basev;
    bias1[c] = basev + s;
}

// ---------------------------------------------------------------------------
// pack fp32 [K][2048] into MFMA b-operand fragments, hi/lo bf16 interleaved:
// out[((kb*128 + nb)*2 + h)*512 + lane*8 + j] ;  k=kb*32+(lane>>4)*8+j ; n=nb*16+(lane&15)
__global__ __launch_bounds__(256) void k_pack(const float* __restrict__ Wt,
                                              short* __restrict__ outp) {
    int idx = blockIdx.x * 256 + threadIdx.x;  // K*2048 elements
    int k = idx >> 11, n = idx & 2047;
    float v = Wt[(size_t)k * 2048 + n];
    short hi = f2bf(v);
    short lo = f2bf(v - bf2f(hi));
    int kb = k >> 5, ks = (k >> 3) & 3, j = k & 7;
    int nb = n >> 4, nl = n & 15;
    int lane = ks * 16 + nl;
    size_t base = (((size_t)kb * 128 + nb) * 2) * 512 + (size_t)lane * 8 + j;
    outp[base] = hi;
    outp[base + 512] = lo;
}

// ---------------------------------------------------------------------------
// half-K GEMM sub-loop: kb in [khalf*8, khalf*8+8); A (bf16 hi/lo) x packed B
__device__ __forceinline__ void gemm_h_half(const short* __restrict__ aH,
                                            const short* __restrict__ aL,
                                            const short* __restrict__ Bp,
                                            int ubG, int lane, int ks, int khalf,
                                            f32x4 acc[4]) {
#pragma unroll 4
    for (int kb2 = 0; kb2 < 8; ++kb2) {
        int kb = khalf * 8 + kb2;
        int ko = kb * 32 + ks * 8;
        short8 ahi = *(const short8*)(aH + ko);
        short8 alo = *(const short8*)(aL + ko);
#pragma unroll
        for (int g = 0; g < 4; ++g) {
            const short* bp = Bp + ((((size_t)kb * 4 + g) * 32) + ubG) * 1024 + (size_t)lane * 8;
            short8 bhi = *(const short8*)bp;
            short8 blo = *(const short8*)(bp + 512);
            acc[g] = __builtin_amdgcn_mfma_f32_16x16x32_bf16(ahi, bhi, acc[g], 0, 0, 0);
            acc[g] = __builtin_amdgcn_mfma_f32_16x16x32_bf16(alo, bhi, acc[g], 0, 0, 0);
            acc[g] = __builtin_amdgcn_mfma_f32_16x16x32_bf16(ahi, blo, acc[g], 0, 0, 0);
        }
    }
}

// ---------------------------------------------------------------------------
// PERSISTENT fused recurrence: one cooperative launch, 65 phases separated by
// grid.sync(). 256 blocks x 512 threads, 1 block/CU (co-resident).
// blockIdx.x < 128 -> panel 0 (layer0 step p); >= 128 -> panel 1 (layer1 p-1).
__global__ __launch_bounds__(512) void k_phases(const int* __restrict__ X,
        const float* __restrict__ C,
        const short* __restrict__ WxP, const short* __restrict__ WcP,
        const short* __restrict__ WhP,
        const float* __restrict__ bias0g, const float* __restrict__ bias1g,
        short* __restrict__ h0H, short* __restrict__ h0L,
        short* __restrict__ h1H, short* __restrict__ h1L,
        float* __restrict__ c0, float* __restrict__ c1) {
    cg::grid_group grid = cg::this_grid();

    const int panel = blockIdx.x >> 7;
    const int bx    = blockIdx.x & 127;
    const int tid   = threadIdx.x;
    const int wave  = tid >> 6, lane = tid & 63;
    const int khalf = wave >> 2, wsub = wave & 3;
    const int lrow  = lane & 15, ks = lane >> 4;
    const int msup  = bx & 3;             // 4 m-supertiles of 64 rows
    const int ubG   = bx >> 2;            // 32 u-blocks of 16 units
    const int row   = msup * 64 + wsub * 16 + lrow;
    const int u     = ubG * 16 + lrow;

    __shared__ float red[4][64][17];      // [wsub][lane][16 + pad]

    // hoisted per-thread constants
    const float* bias = panel ? bias1g : bias0g;
    const float bI = bias[u], bF = bias[512 + u], bG = bias[1024 + u], bO = bias[1536 + u];
    float* cb = panel ? c1 : c0;
    const int rbase = msup * 64 + wsub * 16 + ks * 4;

    for (int p = 0; p <= S; ++p) {
        const bool active = panel ? (p >= 1) : (p < S);
        if (active) {
            f32x4 acc[4];
#pragma unroll
            for (int g = 0; g < 4; ++g) acc[g] = (f32x4){0.f, 0.f, 0.f, 0.f};

            if (panel == 0) {
                // x-part: embedding K=256 -> kb [khalf*4, khalf*4+4)
                const int tok = X[row * S + p];
                const float* crow = C + (size_t)tok * E;
#pragma unroll
                for (int kb2 = 0; kb2 < 4; ++kb2) {
                    int kb = khalf * 4 + kb2;
                    int ko = kb * 32 + ks * 8;
                    float4 v0 = *(const float4*)(crow + ko);
                    float4 v1 = *(const float4*)(crow + ko + 4);
                    float v[8] = {v0.x, v0.y, v0.z, v0.w, v1.x, v1.y, v1.z, v1.w};
                    short8 ahi, alo;
#pragma unroll
                    for (int j = 0; j < 8; ++j) {
                        short hj = f2bf(v[j]);
                        ahi[j] = hj;
                        alo[j] = f2bf(v[j] - bf2f(hj));
                    }
#pragma unroll
                    for (int g = 0; g < 4; ++g) {
                        const short* bp = WxP + ((((size_t)kb * 4 + g) * 32) + ubG) * 1024 + (size_t)lane * 8;
                        short8 bhi = *(const short8*)bp;
                        short8 blo = *(const short8*)(bp + 512);
                        acc[g] = __builtin_amdgcn_mfma_f32_16x16x32_bf16(ahi, bhi, acc[g], 0, 0, 0);
                        acc[g] = __builtin_amdgcn_mfma_f32_16x16x32_bf16(alo, bhi, acc[g], 0, 0, 0);
                        acc[g] = __builtin_amdgcn_mfma_f32_16x16x32_bf16(ahi, blo, acc[g], 0, 0, 0);
                    }
                }
                size_t off = (size_t)((p + 1) & 1) * B * H + (size_t)row * H;
                gemm_h_half(h0H + off, h0L + off, WhP, ubG, lane, ks, khalf, acc);
            } else {
                const int q = p - 1;
                size_t offx = (size_t)(q & 1) * B * H + (size_t)row * H;        // x = h0[q]
                gemm_h_half(h0H + offx, h0L + offx, WcP, ubG, lane, ks, khalf, acc);
                size_t offh = (size_t)((q + 1) & 1) * B * H + (size_t)row * H;  // h1[q-1]
                gemm_h_half(h1H + offh, h1L + offh, WhP, ubG, lane, ks, khalf, acc);
            }

            // combine K-halves: high half deposits; low half reduces + epilogue
            if (khalf == 1) {
#pragma unroll
                for (int g = 0; g < 4; ++g)
#pragma unroll
                    for (int r = 0; r < 4; ++r) red[wsub][lane][g * 4 + r] = acc[g][r];
            }
            __syncthreads();
            if (khalf == 0) {
#pragma unroll
                for (int g = 0; g < 4; ++g)
#pragma unroll
                    for (int r = 0; r < 4; ++r) acc[g][r] += red[wsub][lane][g * 4 + r];

                short* dH; short* dL;
                if (panel == 0) { size_t off = (size_t)(p & 1) * B * H; dH = h0H + off; dL = h0L + off; }
                else            { size_t off = (size_t)((p - 1) & 1) * B * H; dH = h1H + off; dL = h1L + off; }
#pragma unroll
                for (int r = 0; r < 4; ++r) {
                    size_t ix = (size_t)(rbase + r) * H + u;
                    float pi = acc[0][r] + bI;
                    float pf = acc[1][r] + bF;
                    float pg = acc[2][r] + bG;
                    float po = acc[3][r] + bO;
                    float iv = 1.f / (1.f + expf(-pi));
                    float fv = 1.f / (1.f + expf(-pf));
                    float gv = tanhf(pg);
                    float ov = 1.f / (1.f + expf(-po));
                    float cn = fv * cb[ix] + iv * gv;
                    float hn = ov * tanhf(cn);
                    cb[ix] = cn;
                    short hh = f2bf(hn);
                    dH[ix] = hh;
                    dL[ix] = f2bf(hn - bf2f(hh));
                }
            }
        }
        __threadfence();   // device-scope: make h/c visible across XCDs
        grid.sync();
    }
}

// ---------------------------------------------------------------------------
// classifier, double-buffered LDS staging: 500 blocks x 64 n-cols (2 blocks/CU).
// Chunk kc+1 global loads issued before chunk kc MFMAs (latency hidden).
__global__ __launch_bounds__(1024) void k_cls(const short* __restrict__ hH,
                                              const short* __restrict__ hL,
                                              const float* __restrict__ Wf,
                                              const float* __restrict__ bfin,
                                              float* __restrict__ out) {
    const int tid  = threadIdx.x;
    const int wave = tid >> 6, lane = tid & 63;
    const int lrow = lane & 15, ks = lane >> 4;
    const int n0 = blockIdx.x * 64;
    const int m0 = wave * 16;

    __shared__ short BT[2][64 * 64];   // 8 KB each, swizzled: byte ^= (row&7)<<4

    f32x4 acc[4];
#pragma unroll
    for (int nf = 0; nf < 4; ++nf) acc[nf] = (f32x4){0.f, 0.f, 0.f, 0.f};
    const short* aH = hH + (size_t)(m0 + lrow) * H;
    const short* aL = hL + (size_t)(m0 + lrow) * H;

    const int rowl = tid >> 4;          // 64 rows, 16 threads/row
    const int kcol = (tid & 15) * 4;    // 4 k each (float4)
    const int stoff = (rowl * 128 + kcol * 2) ^ ((rowl & 7) << 4);
    const float* wbase = Wf + (size_t)(n0 + rowl) * H + kcol;

    float4 vin = *(const float4*)(wbase);          // prologue: chunk 0
    {
        short4v bw = {f2bf(vin.x), f2bf(vin.y), f2bf(vin.z), f2bf(vin.w)};
        *(short4v*)((char*)BT[0] + stoff) = bw;
    }
    __syncthreads();

    for (int kc = 0; kc < 8; ++kc) {
        if (kc < 7) vin = *(const float4*)(wbase + (kc + 1) * 64);   // prefetch
#pragma unroll
        for (int kbi = 0; kbi < 2; ++kbi) {
            int ko = kc * 64 + kbi * 32 + ks * 8;
            short8 ahi = *(const short8*)(aH + ko);
            short8 alo = *(const short8*)(aL + ko);
#pragma unroll
            for (int nf = 0; nf < 4; ++nf) {
                int nl = nf * 16 + lrow;
                int byte = (nl * 128 + (kbi * 32 + ks * 8) * 2) ^ ((nl & 7) << 4);
                short8 b = *(const short8*)((const char*)BT[kc & 1] + byte);
                acc[nf] = __builtin_amdgcn_mfma_f32_16x16x32_bf16(ahi, b, acc[nf], 0, 0, 0);
                acc[nf] = __builtin_amdgcn_mfma_f32_16x16x32_bf16(alo, b, acc[nf], 0, 0, 0);
            }
        }
        if (kc < 7) {
            short4v bw = {f2bf(vin.x), f2bf(vin.y), f2bf(vin.z), f2bf(vin.w)};
            *(short4v*)((char*)BT[(kc + 1) & 1] + stoff) = bw;
        }
        __syncthreads();
    }

#pragma unroll
    for (int nf = 0; nf < 4; ++nf) {
        int n = n0 + nf * 16 + lrow;
        float bias = bfin[n];
#pragma unroll
        for (int r = 0; r < 4; ++r) {
            int brow = m0 + ks * 4 + r;
            out[(size_t)brow * NC + n] = acc[nf][r] + bias;
        }
    }
}

// ---------------------------------------------------------------------------
extern "C" void kernel_launch(void* const* d_in, const int* in_sizes, int n_in,
                              void* d_out, int out_size, void* d_ws, size_t ws_size,
                              hipStream_t stream) {
    const int*   X    = (const int*)d_in[0];
    const float* C    = (const float*)d_in[1];
    const float* Wii  = (const float*)d_in[2];
    const float* Whi  = (const float*)d_in[3];
    const float* bi   = (const float*)d_in[4];
    const float* Wif  = (const float*)d_in[5];
    const float* Whf  = (const float*)d_in[6];
    const float* bf   = (const float*)d_in[7];
    const float* Wig  = (const float*)d_in[8];
    const float* Whg  = (const float*)d_in[9];
    const float* bg   = (const float*)d_in[10];
    const float* Wio  = (const float*)d_in[11];
    const float* Who  = (const float*)d_in[12];
    const float* bo   = (const float*)d_in[13];
    const float* W    = (const float*)d_in[14];
    const float* bvec = (const float*)d_in[15];
    const float* Wf   = (const float*)d_in[16];
    const float* bfin = (const float*)d_in[17];
    float* out = (float*)d_out;
    char* base = (char*)d_ws;

    // ws layout (bytes), total ~24.1 MB
    float* WhT  = (float*)(base + 0);          // 512*2048*4 = 4,194,304
    float* WxT  = (float*)(base + 4194304);    // 256*2048*4 = 2,097,152
    float* WcT  = (float*)(base + 6291456);    // 4,194,304
    short* WhP  = (short*)(base + 10485760);   // 4,194,304
    short* WxP  = (short*)(base + 14680064);   // 2,097,152
    short* WcP  = (short*)(base + 16777216);   // 4,194,304
    float* bias0 = (float*)(base + 20971520);  // 8192
    float* bias1 = (float*)(base + 20979712);  // 8192
    short* h0H  = (short*)(base + 20987904);   // [2][256][512] bf16 = 524,288 each
    short* h0L  = (short*)(base + 21512192);
    short* h1H  = (short*)(base + 22036480);
    short* h1L  = (short*)(base + 22560768);
    float* c0   = (float*)(base + 23085056);   // 524,288
    float* c1   = (float*)(base + 23609344);   // 524,288

    // zero h-splits (both parities) + cell states: 6*524288 B = 196608 float4
    k_zero<<<768, 256, 0, stream>>>((float4*)(base + 20987904), 196608);

    k_trans<<<dim3(8, 8, 4), 256, 0, stream>>>(Whi, Whf, Whg, Who, H, WhT);
    k_trans<<<dim3(8, 4, 4), 256, 0, stream>>>(Wii, Wif, Wig, Wio, E, WxT);
    k_comb<<<dim3(32, 8), 256, 0, stream>>>(Wii, Wif, Wig, Wio, W, WcT);
    k_pack<<<4096, 256, 0, stream>>>(WhT, WhP);
    k_pack<<<2048, 256, 0, stream>>>(WxT, WxP);
    k_pack<<<4096, 256, 0, stream>>>(WcT, WcP);
    k_bias<<<8, 256, 0, stream>>>(WxT, bi, bf, bg, bo, bvec, bias0, bias1);

    // fused recurrence: one cooperative launch, 65 internal phases
    {
        void* args[] = {(void*)&X, (void*)&C, (void*)&WxP, (void*)&WcP, (void*)&WhP,
                        (void*)&bias0, (void*)&bias1,
                        (void*)&h0H, (void*)&h0L, (void*)&h1H, (void*)&h1L,
                        (void*)&c0, (void*)&c1};
        hipLaunchCooperativeKernel((const void*)k_phases, dim3(256), dim3(512),
                                   args, 0, stream);
    }

    // final h1 (t=63) is in parity 1
    k_cls<<<500, 1024, 0, stream>>>(h1H + (size_t)B * H, h1L + (size_t)B * H, Wf, bfin, out);
}